// Round 4
// baseline (336.977 us; speedup 1.0000x reference)
//
#include <hip/hip_runtime.h>
#include <hip/hip_cooperative_groups.h>
#include <cstdint>
#include <cstddef>

namespace cgrp = cooperative_groups;

#define NLV 5
#define NIMG 4
#define NSEL 4507          // 1000+1000+1000+1000+507 selected per image
#define TSEL (NIMG * NSEL)
#define POSTN 1000
#define TCAP 8192          // boundary-bin candidate cap
#define TTCAP 2048         // sub-boundary (tie-of-tie) cap
#define NHB 16             // sub-histograms per (image,level)
#define PBLK 64            // pick units per (image,level)
#define PCH 1875           // max chunk for pick (120000/64)
#define NTRI 136           // upper-triangle 64x64 tiles (nw<=16)
#define GRID 256           // cooperative grid: 1 block/CU on MI355X

__device__ const int d_W[NLV]    = {200, 100, 50, 25, 13};
__device__ const int d_NL[NLV]   = {120000, 30000, 7500, 1875, 507};
__device__ const int d_KOFF[6]   = {0, 120000, 150000, 157500, 159375, 159882};
__device__ const int d_LOFF[6]   = {0, 1000, 2000, 3000, 4000, 4507};
__device__ const int d_KL[NLV]   = {1000, 1000, 1000, 1000, 507};

struct Ptrs {
    const float* obj[NLV];
    const float* del[NLV];
    const float* anch;
};

// order-preserving map: dk ascending <=> float descending
__device__ inline unsigned int dkey_of(float f) {
    unsigned int u = __float_as_uint(f);
    unsigned int mk = (u & 0x80000000u) ? ~u : (u | 0x80000000u);
    return ~mk;
}
__device__ inline float logit_from_dkey(unsigned int dk) {
    unsigned int mk = ~dk;
    unsigned int u = (mk & 0x80000000u) ? (mk & 0x7fffffffu) : ~mk;
    return __uint_as_float(u);
}

// ============================================================================
// Cooperative mega-kernel: all 7 stages, 6 grid syncs, 1 dispatch.
// Each stage keeps its proven parallelism mapping (rounds 1-3 lessons:
// never serialize chip-wide stages; hist keeps 256-thr-per-private-hist).
// ============================================================================
__global__ __launch_bounds__(1024) void k_all(Ptrs P,
        unsigned int* hist, int* scnt, int* tcnt, unsigned int* thr,
        unsigned long long* tiebuf, int* cgv, float* clv,
        unsigned long long* skey, float4* sboxL, float* slogL,
        int* ccnt, unsigned long long* keepL, unsigned long long* MT,
        float* out) {
#pragma clang fp contract(off)
    cgrp::grid_group gg = cgrp::this_grid();
    int bid = blockIdx.x, tid = threadIdx.x;
    int w = tid >> 6, lane = tid & 63;

    __shared__ union {
        unsigned int h4[4][2048];                     // 32KB hist (4 groups)
        struct { int sp[PCH]; float sl[PCH];
                 unsigned long long tb[PCH]; } pk;    // 30KB pick
        struct { unsigned long long kk[TCAP];
                 unsigned long long tt[TTCAP];
                 unsigned int h2[2048]; } tie;        // 88KB tie (max member)
        struct { unsigned long long s[1024]; float4 bx[1024];
                 float lg[1024]; } srt;               // 28KB sort
        struct { float4 bi[64]; float4 bj[64]; } mk;  //  2KB mask
        unsigned long long KS[NLV][1024];             // 40KB rank
    } U;
    __shared__ unsigned int wpre[16];
    __shared__ unsigned int s_b1, s_before;
    __shared__ int ctr, ttc;
    __shared__ int nselS, ntieS, sbaseS, tbaseS;
    __shared__ unsigned long long pendS[16], defS[16];
    __shared__ unsigned long long kd[NLV][16];
    __shared__ int kpre[NLV][17];
    __shared__ int lcnt[NLV];

    // ======== stage 0: histograms (320 x 256-thr groups) + out zero ========
    {
        for (int i = tid; i < 4 * 2048; i += 1024) ((unsigned int*)U.h4)[i] = 0;
        __syncthreads();
        int g = bid * 4 + (tid >> 8);                 // group slot 0..1023
        int tsub = tid & 255;
        int u = ((g % 3) == 0 && (g / 3) < 320) ? (g / 3) : -1;  // spread units
        int nlid = -1, l = 0, n = 0, sub = 0;
        if (u >= 0) {
            nlid = u >> 4; sub = u & 15;
            n = nlid / NLV; l = nlid % NLV;
            if (d_KL[l] >= d_NL[l]) nlid = -1;        // level 4: all selected
        }
        if (nlid >= 0) {
            int nl_sz = d_NL[l];
            const float* ob = P.obj[l] + (size_t)n * nl_sz;
            int chunk = (nl_sz + NHB - 1) / NHB;
            int beg = sub * chunk, end = min(beg + chunk, nl_sz);
            unsigned int* hh = U.h4[tid >> 8];
            for (int t = beg + tsub; t < end; t += 256)
                atomicAdd(&hh[dkey_of(ob[t]) >> 21], 1u);   // LDS atomic
        }
        __syncthreads();
        if (nlid >= 0) {
            unsigned int* hh = U.h4[tid >> 8];
            unsigned int* op = hist + ((size_t)nlid * NHB + sub) * 2048;
            for (int i = tsub; i < 2048; i += 256) op[i] = hh[i];
        }
        if (bid >= GRID - 16) {                       // blocks 240..255: no units
            int z = (bid - (GRID - 16)) * 1024 + tid;
            if (z < NIMG * POSTN) {
                ((float4*)out)[z] = make_float4(0.f, 0.f, 0.f, 0.f);
                out[NIMG * POSTN * 4 + z] = 0.f;
            }
        }
    }
    gg.sync();

    // ======== stage 1: reduce sub-hists, boundary bin (20 blocks) ==========
    if (bid < NIMG * NLV) {
        int nlid = bid, l = nlid % NLV;
        if (tid == 0) { scnt[nlid] = 0; tcnt[nlid] = 0; }
        if (d_KL[l] < d_NL[l]) {
            const unsigned int* hb = hist + (size_t)nlid * NHB * 2048;
            unsigned int v0 = 0, v1 = 0;
            #pragma unroll
            for (int sh = 0; sh < NHB; ++sh) {
                v0 += hb[sh * 2048 + 2 * tid];
                v1 += hb[sh * 2048 + 2 * tid + 1];
            }
            unsigned int s = v0 + v1, ps = s;
            #pragma unroll
            for (int d = 1; d < 64; d <<= 1) {
                unsigned int t2 = (unsigned int)__shfl_up((int)ps, d, 64);
                if (lane >= d) ps += t2;
            }
            if (lane == 63) wpre[w] = ps;
            __syncthreads();
            unsigned int base = 0;
            #pragma unroll
            for (int ww = 0; ww < 16; ++ww) if (ww < w) base += wpre[ww];
            unsigned int incl = base + ps;            // inclusive prefix over PAIRS
            unsigned int target = (unsigned int)d_KL[l];
            unsigned int exc0 = incl - s, inc0 = incl - v1;
            unsigned int exc1 = inc0,    inc1 = incl;
            if (exc0 < target && target <= inc0) { thr[nlid * 2] = 2 * tid;     thr[nlid * 2 + 1] = exc0; }
            if (exc1 < target && target <= inc1) { thr[nlid * 2] = 2 * tid + 1; thr[nlid * 2 + 1] = exc1; }
        }
    }
    gg.sync();

    // ======== stage 2: pick winners (1280 units, 5 per block) ==============
    for (int pass = 0; pass < 5; ++pass) {
        int unit = pass * GRID + bid;                 // 0..1279
        int nlid = unit >> 6, pb = unit & 63;
        int n = nlid / NLV, l = nlid % NLV;
        int nl_sz = d_NL[l], kl = d_KL[l];
        const float* ob = P.obj[l] + (size_t)n * nl_sz;
        int cbase = n * NSEL + d_LOFF[l];
        int koff = d_KOFF[l];
        int Wl = d_W[l], HW = Wl * Wl;
        int chunk = (nl_sz + PBLK - 1) / PBLK;
        int beg = pb * chunk, end = min(beg + chunk, nl_sz);

        if (kl >= nl_sz) {                            // level 4: deterministic
            for (int t = beg + tid; t < end; t += 1024) {
                int a = t / HW, rem = t - a * HW;
                int p = rem * 3 + a;
                cgv[cbase + p] = koff + p;
                clv[cbase + p] = ob[t];
            }
            continue;                                 // block-uniform
        }
        if (tid == 0) { nselS = 0; ntieS = 0; }
        __syncthreads();                              // also fences prev pass LDS reads
        unsigned int b0 = thr[nlid * 2];
        for (int t = beg + tid; t < end; t += 1024) {
            float lg = ob[t];
            unsigned int dk = dkey_of(lg);
            unsigned int bin = dk >> 21;
            if (bin < b0) {
                int pos = atomicAdd(&nselS, 1);       // LDS atomic (rare)
                int a = t / HW, rem = t - a * HW;
                U.pk.sp[pos] = rem * 3 + a;
                U.pk.sl[pos] = lg;
            } else if (bin == b0) {
                int pos = atomicAdd(&ntieS, 1);
                int a = t / HW, rem = t - a * HW;
                U.pk.tb[pos] = ((unsigned long long)dk << 17) |
                               (unsigned long long)(unsigned int)(rem * 3 + a);
            }
        }
        __syncthreads();
        if (tid == 0) {
            sbaseS = atomicAdd(&scnt[nlid], nselS);   // 1 global atomic / unit
            tbaseS = atomicAdd(&tcnt[nlid], ntieS);
        }
        __syncthreads();
        int ns = nselS, nt2 = ntieS, sb = sbaseS, tb2 = tbaseS;
        for (int i = tid; i < ns; i += 1024) {
            cgv[cbase + sb + i] = koff + U.pk.sp[i];
            clv[cbase + sb + i] = U.pk.sl[i];
        }
        for (int i = tid; i < nt2; i += 1024) {
            int slot = tb2 + i;
            if (slot < TCAP) tiebuf[(size_t)nlid * TCAP + slot] = U.pk.tb[i];
        }
    }
    gg.sync();

    // ======== stage 3: tie + build + sort (20 blocks) ======================
    if (bid < NIMG * NLV) {
        int nlid = bid;
        int n = nlid / NLV, l = nlid % NLV;
        int kl = d_KL[l], nl_sz = d_NL[l];
        int cbase = n * NSEL + d_LOFF[l];
        int koff = d_KOFF[l];

        // ---- phase A: boundary-bin candidates, radix-refined ----
        if (kl < nl_sz) {
            int c = min(tcnt[nlid], TCAP);
            unsigned int cnt_lt = thr[nlid * 2 + 1];
            int need = kl - (int)cnt_lt;
            if (tid == 0) { ctr = 0; ttc = 0; }
            U.tie.h2[tid] = 0; U.tie.h2[tid + 1024] = 0;
            for (int i = tid; i < c; i += 1024) U.tie.kk[i] = tiebuf[(size_t)nlid * TCAP + i];
            __syncthreads();
            for (int i = tid; i < c; i += 1024)
                atomicAdd(&U.tie.h2[(unsigned int)((U.tie.kk[i] >> 27) & 0x7ffull)], 1u);
            __syncthreads();
            unsigned int v0 = U.tie.h2[2 * tid], v1 = U.tie.h2[2 * tid + 1];
            unsigned int s = v0 + v1, ps = s;
            #pragma unroll
            for (int d = 1; d < 64; d <<= 1) {
                unsigned int t2 = (unsigned int)__shfl_up((int)ps, d, 64);
                if (lane >= d) ps += t2;
            }
            if (lane == 63) wpre[w] = ps;
            __syncthreads();
            unsigned int base = 0;
            #pragma unroll
            for (int ww = 0; ww < 16; ++ww) if (ww < w) base += wpre[ww];
            unsigned int incl = base + ps;
            unsigned int target = (unsigned int)need;
            unsigned int exc0 = incl - s, inc0 = incl - v1;
            unsigned int exc1 = inc0,    inc1 = incl;
            if (exc0 < target && target <= inc0) { s_b1 = 2 * tid;     s_before = exc0; }
            if (exc1 < target && target <= inc1) { s_b1 = 2 * tid + 1; s_before = exc1; }
            __syncthreads();
            unsigned int b1 = s_b1;
            int before = (int)s_before;
            for (int i = tid; i < c; i += 1024) {
                unsigned long long ki = U.tie.kk[i];
                unsigned int sb = (unsigned int)((ki >> 27) & 0x7ffull);
                if (sb < b1) {                        // sure winner
                    int slot = atomicAdd(&ctr, 1);
                    int p = (int)(ki & 0x1ffffull);
                    cgv[cbase + (int)cnt_lt + slot] = koff + p;
                    clv[cbase + (int)cnt_lt + slot] = logit_from_dkey((unsigned int)(ki >> 17));
                } else if (sb == b1) {
                    int j = atomicAdd(&ttc, 1);
                    if (j < TTCAP) U.tie.tt[j] = ki;
                }
            }
            __syncthreads();
            int c2 = min(ttc, TTCAP);
            int need2 = need - before;
            for (int i = tid; i < c2; i += 1024) {
                unsigned long long ki = U.tie.tt[i];
                int rank = 0;
                for (int j = 0; j < c2; ++j) rank += (U.tie.tt[j] < ki) ? 1 : 0;
                if (rank < need2) {                   // ranks unique (p unique)
                    int p = (int)(ki & 0x1ffffull);
                    cgv[cbase + (int)cnt_lt + before + rank] = koff + p;
                    clv[cbase + (int)cnt_lt + before + rank] = logit_from_dkey((unsigned int)(ki >> 17));
                }
            }
        }
        __syncthreads();   // phase A LDS dead; cg/cl visible block-wide

        // ---- phase B: decode, clip, validity ----
        {
            int j = tid;
            unsigned long long key;
            float4 box;
            float lgv;
            if (j >= kl) {                            // padding slot
                key = ((unsigned long long)0xFFFFFFFFu << 27) | (unsigned long long)j;
                box = make_float4(0.f, 0.f, 0.f, 0.f);
                lgv = 0.f;
            } else {
                int sidx = cbase + j;
                int gidx = cgv[sidx];
                float lg = clv[sidx];
                int p = gidx - koff;
                int Wl = d_W[l];
                int HW = Wl * Wl;
                int a = p % 3, hw = p / 3;
                int hq = hw / Wl, wq = hw - hq * Wl;
                const float* dl = P.del[l];
                size_t dbase = (size_t)(n * 12 + a * 4) * HW + (size_t)hq * Wl + wq;
                float dx = dl[dbase], dy = dl[dbase + HW];
                float dw = dl[dbase + 2 * (size_t)HW], dh = dl[dbase + 3 * (size_t)HW];
                const float* an = P.anch + 4 * (size_t)gidx;
                float ax1 = an[0], ay1 = an[1], ax2 = an[2], ay2 = an[3];
                float wa = ax2 - ax1, ha = ay2 - ay1;
                float cxa = ax1 + 0.5f * wa, cya = ay1 + 0.5f * ha;
                const float CLIPC = (float)4.135166556742356;
                dw = fminf(dw, CLIPC); dh = fminf(dh, CLIPC);
                float cx = dx * wa + cxa;
                float cy = dy * ha + cya;
                float ww2 = expf(dw) * wa;
                float hh2 = expf(dh) * ha;
                float x1 = cx - 0.5f * ww2, y1 = cy - 0.5f * hh2;
                float x2 = cx + 0.5f * ww2, y2 = cy + 0.5f * hh2;
                x1 = fminf(fmaxf(x1, 0.0f), 800.0f);
                y1 = fminf(fmaxf(y1, 0.0f), 800.0f);
                x2 = fminf(fmaxf(x2, 0.0f), 800.0f);
                y2 = fminf(fmaxf(y2, 0.0f), 800.0f);
                bool valid = (x2 - x1 >= 1e-3f) && (y2 - y1 >= 1e-3f);
                box = make_float4(x1, y1, x2, y2);
                lgv = lg;
                unsigned int sk = valid ? dkey_of(lg) : 0xffffffffu;
                key = ((unsigned long long)sk << 27) |
                      ((unsigned long long)(unsigned int)p << 10) | (unsigned long long)j;
            }
            U.srt.s[j] = key;
            U.srt.bx[j] = box;
            U.srt.lg[j] = lgv;
        }
        __syncthreads();

        // ---- phase C: bitonic sort of 1024 keys (512 active) ----
        for (int k = 2; k <= 1024; k <<= 1) {
            for (int j2 = k >> 1; j2 > 0; j2 >>= 1) {
                if (tid < 512) {
                    int i = ((tid & ~(j2 - 1)) << 1) | (tid & (j2 - 1));
                    int ix = i | j2;
                    bool up = ((i & k) == 0);
                    unsigned long long A = U.srt.s[i], B = U.srt.s[ix];
                    if ((A > B) == up) { U.srt.s[i] = B; U.srt.s[ix] = A; }
                }
                __syncthreads();
            }
        }
        {
            int e = tid;
            unsigned long long key = U.srt.s[e];
            int j = (int)(key & 0x3ffull);
            skey[(size_t)nlid * 1024 + e] = key;
            sboxL[(size_t)nlid * 1024 + e] = U.srt.bx[j];
            slogL[(size_t)nlid * 1024 + e] = U.srt.lg[j];
            bool v = (key >> 27) != 0xFFFFFFFFull;
            bool vn = (e < 1023) ? ((U.srt.s[e + 1] >> 27) != 0xFFFFFFFFull) : false;
            if (e == 0 && !v) ccnt[nlid] = 0;
            if (v && (e == 1023 || !vn)) ccnt[nlid] = e + 1;
        }
    }
    gg.sync();

    // ======== stage 4: pairwise IoU mask (2720 tiles, chip-wide) ===========
    for (int T = bid; T < NIMG * NLV * NTRI; T += GRID) {
        int nl = T / NTRI, t136 = T - nl * NTRI;
        int cnt = ccnt[nl];
        int nw = (cnt + 63) / 64;
        int cj = 0;
        while (((cj + 1) * (cj + 2)) >> 1 <= t136) ++cj;
        int ci = t136 - ((cj * (cj + 1)) >> 1);
        if (cj >= nw) continue;                       // block-uniform
        int l = nl % NLV;
        float off = (float)l * 801.0f;
        __syncthreads();                              // prev tile reads done
        if (tid < 64) {
            float4 b = sboxL[(size_t)nl * 1024 + cj * 64 + tid];
            U.mk.bj[tid] = make_float4(b.x + off, b.y + off, b.z + off, b.w + off);
        } else if (tid < 128) {
            float4 b = sboxL[(size_t)nl * 1024 + ci * 64 + (tid - 64)];
            U.mk.bi[tid - 64] = make_float4(b.x + off, b.y + off, b.z + off, b.w + off);
        }
        __syncthreads();
        float4 B = U.mk.bj[lane];
        float a2 = (B.z - B.x) * (B.w - B.y);
        unsigned long long* outp = MT + ((size_t)nl * 16 + cj) * 1024 + ci * 64;
        #pragma unroll
        for (int t = 0; t < 4; ++t) {                 // 16 waves x 4 rows = 64
            int i = w * 4 + t;
            float4 A = U.mk.bi[i];
            float a1 = (A.z - A.x) * (A.w - A.y);
            float ltx = fmaxf(A.x, B.x), lty = fmaxf(A.y, B.y);
            float rbx = fminf(A.z, B.z), rby = fminf(A.w, B.w);
            float wx = fmaxf(rbx - ltx, 0.f), wy = fmaxf(rby - lty, 0.f);
            float inter = wx * wy;
            float iou = inter / ((a1 + a2) - inter);  // NaN (0/0) -> false
            unsigned long long word = __ballot(iou > 0.7f);
            if (lane == 0) outp[i] = word;
        }
    }
    gg.sync();

    // ======== stage 5: greedy NMS fixpoint scan (20 blocks) ================
    if (bid < NIMG * NLV) {
        int nl = bid;
        int cnt = ccnt[nl];
        int nw = (cnt + 63) / 64;
        const unsigned long long* base = MT + ((size_t)nl * 16 + w) * 1024;
        unsigned long long Dmask = 0;
        if (w < nw)
            Dmask = base[(size_t)w * 64 + lane] & ~((2ull << lane) - 1ull);
        unsigned long long rows[15];
        #pragma unroll
        for (int cc = 0; cc < 15; ++cc)
            rows[cc] = (cc < w && w < nw) ? base[(size_t)cc * 64 + lane] : 0ull;

        int nb = max(0, min(64, cnt - w * 64));
        unsigned long long pend_w = (nb == 64) ? ~0ull : ((nb > 0) ? ((1ull << nb) - 1ull) : 0ull);
        unsigned long long K_w = 0;
        if (lane == 0) pendS[w] = pend_w;
        __syncthreads();

        for (int round = 0; round < 1024; ++round) {
            unsigned long long any = 0;
            #pragma unroll
            for (int cc = 0; cc < 16; ++cc) any |= pendS[cc];
            if (!any) break;
            unsigned long long acc = ((pendS[w] >> lane) & 1ull) ? Dmask : 0ull;
            #pragma unroll
            for (int cc = 0; cc < 15; ++cc)
                if (cc < w) acc |= ((pendS[cc] >> lane) & 1ull) ? rows[cc] : 0ull;
            unsigned int vlo = (unsigned int)acc, vhi = (unsigned int)(acc >> 32);
            #pragma unroll
            for (int m = 1; m < 64; m <<= 1) {
                vlo |= (unsigned int)__shfl_xor((int)vlo, m, 64);
                vhi |= (unsigned int)__shfl_xor((int)vhi, m, 64);
            }
            unsigned long long sup = ((unsigned long long)vhi << 32) | (unsigned long long)vlo;
            unsigned long long def_w = pend_w & ~sup;
            K_w |= def_w;
            if (lane == 0) defS[w] = def_w;
            __syncthreads();
            unsigned long long acc2 = ((defS[w] >> lane) & 1ull) ? Dmask : 0ull;
            #pragma unroll
            for (int cc = 0; cc < 15; ++cc)
                if (cc < w) acc2 |= ((defS[cc] >> lane) & 1ull) ? rows[cc] : 0ull;
            unsigned int rlo = (unsigned int)acc2, rhi = (unsigned int)(acc2 >> 32);
            #pragma unroll
            for (int m = 1; m < 64; m <<= 1) {
                rlo |= (unsigned int)__shfl_xor((int)rlo, m, 64);
                rhi |= (unsigned int)__shfl_xor((int)rhi, m, 64);
            }
            unsigned long long rem = ((unsigned long long)rhi << 32) | (unsigned long long)rlo;
            pend_w &= ~def_w & ~rem;
            if (lane == 0) pendS[w] = pend_w;
            __syncthreads();
        }
        if (lane == 0) keepL[nl * 16 + w] = K_w;
    }
    gg.sync();

    // ======== stage 6: rank-merge (20 blocks) ==============================
    // Score ties across levels: reference tiebreak is level asc — bounds
    // compare sk only: l2<l counts sk'<=sk, l2>l counts sk'<sk.
    if (bid < NIMG * NLV) {
        int l = bid % NLV, n = bid / NLV;
        for (int e = tid; e < NLV * 1024; e += 1024)
            ((unsigned long long*)U.KS)[e] = skey[(size_t)n * NLV * 1024 + e];
        if (tid < NLV * 16) ((unsigned long long*)kd)[tid] = keepL[n * NLV * 16 + tid];
        if (tid < NLV) lcnt[tid] = ccnt[n * NLV + tid];
        __syncthreads();
        if (tid < NLV) {
            int run = 0;
            for (int q = 0; q < 16; ++q) { kpre[tid][q] = run; run += (int)__popcll(kd[tid][q]); }
            kpre[tid][16] = run;
        }
        __syncthreads();
        int i = tid;
        if (i < lcnt[l]) {
            int q = i >> 6, b = i & 63;
            if ((kd[l][q] >> b) & 1ull) {
                int rank = kpre[l][q] + (int)__popcll(kd[l][q] & ((1ull << b) - 1ull));
                unsigned int sk = (unsigned int)(U.KS[l][i] >> 27);
                for (int l2 = 0; l2 < NLV; ++l2) {
                    if (l2 == l) continue;
                    int c2 = lcnt[l2];
                    unsigned long long bound = (l2 < l)
                        ? (((unsigned long long)sk + 1ull) << 27)   // sk' <= sk
                        : ((unsigned long long)sk << 27);           // sk' <  sk
                    int lo = 0, hi = c2;
                    while (lo < hi) {
                        int mid = (lo + hi) >> 1;
                        if (U.KS[l2][mid] < bound) lo = mid + 1; else hi = mid;
                    }
                    int mq = lo >> 6, mb = lo & 63;
                    rank += kpre[l2][mq] + (mb ? (int)__popcll(kd[l2][mq] & ((1ull << mb) - 1ull)) : 0);
                }
                if (rank < POSTN) {
                    ((float4*)out)[n * POSTN + rank] = sboxL[(size_t)(n * NLV + l) * 1024 + i];
                    float lg = slogL[(size_t)(n * NLV + l) * 1024 + i];
                    out[NIMG * POSTN * 4 + n * POSTN + rank] = 1.0f / (1.0f + expf(-lg));
                }
            }
        }
    }
}

// ============================================================================
// Fallback: proven round-3 7-kernel pipeline (used if cooperative launch
// is rejected by the runtime/capture).
// ============================================================================
__global__ __launch_bounds__(256) void k_hist(Ptrs P, unsigned int* hist) {
    int l = blockIdx.y, n = blockIdx.z;
    int nl_sz = d_NL[l];
    if (d_KL[l] >= nl_sz) return;
    int nlid = n * NLV + l;
    __shared__ unsigned int h[2048];
    for (int i = threadIdx.x; i < 2048; i += 256) h[i] = 0;
    __syncthreads();
    const float* ob = P.obj[l] + (size_t)n * nl_sz;
    int chunk = (nl_sz + NHB - 1) / NHB;
    int beg = blockIdx.x * chunk;
    int end = min(beg + chunk, nl_sz);
    for (int t = beg + (int)threadIdx.x; t < end; t += 256)
        atomicAdd(&h[dkey_of(ob[t]) >> 21], 1u);
    __syncthreads();
    unsigned int* out = hist + ((size_t)nlid * NHB + blockIdx.x) * 2048;
    for (int i = threadIdx.x; i < 2048; i += 256) out[i] = h[i];
}

__global__ __launch_bounds__(1024) void k_thresh(const unsigned int* hist,
                                                 unsigned int* thr,
                                                 int* scnt, int* tcnt) {
    int nlid = blockIdx.x;
    int l = nlid % NLV;
    if (threadIdx.x == 0) { scnt[nlid] = 0; tcnt[nlid] = 0; }
    if (d_KL[l] >= d_NL[l]) return;
    int tid = threadIdx.x, w = tid >> 6, lane = tid & 63;
    __shared__ unsigned int wpre[16];
    const unsigned int* hb = hist + (size_t)nlid * NHB * 2048;
    unsigned int v0 = 0, v1 = 0;
    #pragma unroll
    for (int sh = 0; sh < NHB; ++sh) {
        v0 += hb[sh * 2048 + 2 * tid];
        v1 += hb[sh * 2048 + 2 * tid + 1];
    }
    unsigned int s = v0 + v1;
    unsigned int ps = s;
    #pragma unroll
    for (int d = 1; d < 64; d <<= 1) {
        unsigned int t2 = (unsigned int)__shfl_up((int)ps, d, 64);
        if (lane >= d) ps += t2;
    }
    if (lane == 63) wpre[w] = ps;
    __syncthreads();
    unsigned int base = 0;
    #pragma unroll
    for (int ww = 0; ww < 16; ++ww) if (ww < w) base += wpre[ww];
    unsigned int incl = base + ps;
    unsigned int target = (unsigned int)d_KL[l];
    unsigned int exc0 = incl - s, inc0 = incl - v1;
    unsigned int exc1 = inc0,    inc1 = incl;
    if (exc0 < target && target <= inc0) { thr[nlid * 2] = 2 * tid;     thr[nlid * 2 + 1] = exc0; }
    if (exc1 < target && target <= inc1) { thr[nlid * 2] = 2 * tid + 1; thr[nlid * 2 + 1] = exc1; }
}

__global__ __launch_bounds__(256) void k_pick(Ptrs P, const unsigned int* thr,
                                              int* scnt, int* tcnt,
                                              int* cgv, float* clv,
                                              unsigned long long* tiebuf) {
    int l = blockIdx.y, n = blockIdx.z;
    int nl_sz = d_NL[l], kl = d_KL[l];
    int nlid = n * NLV + l;
    const float* ob = P.obj[l] + (size_t)n * nl_sz;
    int cbase = n * NSEL + d_LOFF[l];
    int koff = d_KOFF[l];
    int Wl = d_W[l], HW = Wl * Wl;
    int chunk = (nl_sz + PBLK - 1) / PBLK;
    int beg = blockIdx.x * chunk;
    int end = min(beg + chunk, nl_sz);
    int tid = threadIdx.x;

    if (kl >= nl_sz) {
        for (int t = beg + tid; t < end; t += 256) {
            int a = t / HW, rem = t - a * HW;
            int p = rem * 3 + a;
            cgv[cbase + p] = koff + p;
            clv[cbase + p] = ob[t];
        }
        return;
    }
    __shared__ int sp[PCH];
    __shared__ float sl[PCH];
    __shared__ unsigned long long tb[PCH];
    __shared__ int nsel, ntie, sbase, tbase;
    if (tid == 0) { nsel = 0; ntie = 0; }
    __syncthreads();

    unsigned int b0 = thr[nlid * 2];
    for (int t = beg + tid; t < end; t += 256) {
        float lg = ob[t];
        unsigned int dk = dkey_of(lg);
        unsigned int bin = dk >> 21;
        if (bin < b0) {
            int pos = atomicAdd(&nsel, 1);
            int a = t / HW, rem = t - a * HW;
            sp[pos] = rem * 3 + a;
            sl[pos] = lg;
        } else if (bin == b0) {
            int pos = atomicAdd(&ntie, 1);
            int a = t / HW, rem = t - a * HW;
            tb[pos] = ((unsigned long long)dk << 17) |
                      (unsigned long long)(unsigned int)(rem * 3 + a);
        }
    }
    __syncthreads();
    if (tid == 0) {
        sbase = atomicAdd(&scnt[nlid], nsel);
        tbase = atomicAdd(&tcnt[nlid], ntie);
    }
    __syncthreads();
    int ns = nsel, nt = ntie, sb = sbase, tbs = tbase;
    for (int i = tid; i < ns; i += 256) {
        cgv[cbase + sb + i] = koff + sp[i];
        clv[cbase + sb + i] = sl[i];
    }
    for (int i = tid; i < nt; i += 256) {
        int slot = tbs + i;
        if (slot < TCAP) tiebuf[(size_t)nlid * TCAP + slot] = tb[i];
    }
}

__global__ __launch_bounds__(1024) void k_tbs(Ptrs P, const unsigned int* thr,
                                              const int* tcnt,
                                              const unsigned long long* tiebuf,
                                              int* cgv, float* clv,
                                              unsigned long long* skey,
                                              float4* sboxL, float* slogL,
                                              int* ccnt) {
#pragma clang fp contract(off)
    __shared__ union {
        struct { unsigned long long kk[TCAP];
                 unsigned long long tt[TTCAP];
                 unsigned int h2[2048]; } tie;
        struct { unsigned long long s[1024];
                 float4 bx[1024];
                 float lg[1024]; } srt;
    } U;
    __shared__ unsigned int wpre[16];
    __shared__ unsigned int s_b1, s_before;
    __shared__ int ctr, ttc;

    int l = blockIdx.x, n = blockIdx.y;
    int nl = n * NLV + l;
    int tid = threadIdx.x, w = tid >> 6, lane = tid & 63;
    int kl = d_KL[l], nl_sz = d_NL[l];
    int cbase = n * NSEL + d_LOFF[l];
    int koff = d_KOFF[l];

    if (kl < nl_sz) {
        int c = min(tcnt[nl], TCAP);
        unsigned int cnt_lt = thr[nl * 2 + 1];
        int need = kl - (int)cnt_lt;
        if (tid == 0) { ctr = 0; ttc = 0; }
        U.tie.h2[tid] = 0; U.tie.h2[tid + 1024] = 0;
        for (int i = tid; i < c; i += 1024) U.tie.kk[i] = tiebuf[(size_t)nl * TCAP + i];
        __syncthreads();
        for (int i = tid; i < c; i += 1024)
            atomicAdd(&U.tie.h2[(unsigned int)((U.tie.kk[i] >> 27) & 0x7ffull)], 1u);
        __syncthreads();
        unsigned int v0 = U.tie.h2[2 * tid], v1 = U.tie.h2[2 * tid + 1];
        unsigned int s = v0 + v1, ps = s;
        #pragma unroll
        for (int d = 1; d < 64; d <<= 1) {
            unsigned int t2 = (unsigned int)__shfl_up((int)ps, d, 64);
            if (lane >= d) ps += t2;
        }
        if (lane == 63) wpre[w] = ps;
        __syncthreads();
        unsigned int base = 0;
        #pragma unroll
        for (int ww = 0; ww < 16; ++ww) if (ww < w) base += wpre[ww];
        unsigned int incl = base + ps;
        unsigned int target = (unsigned int)need;
        unsigned int exc0 = incl - s, inc0 = incl - v1;
        unsigned int exc1 = inc0,    inc1 = incl;
        if (exc0 < target && target <= inc0) { s_b1 = 2 * tid;     s_before = exc0; }
        if (exc1 < target && target <= inc1) { s_b1 = 2 * tid + 1; s_before = exc1; }
        __syncthreads();
        unsigned int b1 = s_b1;
        int before = (int)s_before;
        for (int i = tid; i < c; i += 1024) {
            unsigned long long ki = U.tie.kk[i];
            unsigned int sb = (unsigned int)((ki >> 27) & 0x7ffull);
            if (sb < b1) {
                int slot = atomicAdd(&ctr, 1);
                int p = (int)(ki & 0x1ffffull);
                cgv[cbase + (int)cnt_lt + slot] = koff + p;
                clv[cbase + (int)cnt_lt + slot] = logit_from_dkey((unsigned int)(ki >> 17));
            } else if (sb == b1) {
                int j = atomicAdd(&ttc, 1);
                if (j < TTCAP) U.tie.tt[j] = ki;
            }
        }
        __syncthreads();
        int c2 = min(ttc, TTCAP);
        int need2 = need - before;
        for (int i = tid; i < c2; i += 1024) {
            unsigned long long ki = U.tie.tt[i];
            int rank = 0;
            for (int j = 0; j < c2; ++j) rank += (U.tie.tt[j] < ki) ? 1 : 0;
            if (rank < need2) {
                int p = (int)(ki & 0x1ffffull);
                cgv[cbase + (int)cnt_lt + before + rank] = koff + p;
                clv[cbase + (int)cnt_lt + before + rank] = logit_from_dkey((unsigned int)(ki >> 17));
            }
        }
    }
    __syncthreads();

    {
        int j = tid;
        unsigned long long key;
        float4 box;
        float lgv;
        if (j >= kl) {
            key = ((unsigned long long)0xFFFFFFFFu << 27) | (unsigned long long)j;
            box = make_float4(0.f, 0.f, 0.f, 0.f);
            lgv = 0.f;
        } else {
            int sidx = cbase + j;
            int gidx = cgv[sidx];
            float lg = clv[sidx];
            int p = gidx - koff;
            int Wl = d_W[l];
            int HW = Wl * Wl;
            int a = p % 3, hw = p / 3;
            int hq = hw / Wl, wq = hw - hq * Wl;
            const float* dl = P.del[l];
            size_t dbase = (size_t)(n * 12 + a * 4) * HW + (size_t)hq * Wl + wq;
            float dx = dl[dbase], dy = dl[dbase + HW];
            float dw = dl[dbase + 2 * (size_t)HW], dh = dl[dbase + 3 * (size_t)HW];
            const float* an = P.anch + 4 * (size_t)gidx;
            float ax1 = an[0], ay1 = an[1], ax2 = an[2], ay2 = an[3];
            float wa = ax2 - ax1, ha = ay2 - ay1;
            float cxa = ax1 + 0.5f * wa, cya = ay1 + 0.5f * ha;
            const float CLIPC = (float)4.135166556742356;
            dw = fminf(dw, CLIPC); dh = fminf(dh, CLIPC);
            float cx = dx * wa + cxa;
            float cy = dy * ha + cya;
            float ww2 = expf(dw) * wa;
            float hh2 = expf(dh) * ha;
            float x1 = cx - 0.5f * ww2, y1 = cy - 0.5f * hh2;
            float x2 = cx + 0.5f * ww2, y2 = cy + 0.5f * hh2;
            x1 = fminf(fmaxf(x1, 0.0f), 800.0f);
            y1 = fminf(fmaxf(y1, 0.0f), 800.0f);
            x2 = fminf(fmaxf(x2, 0.0f), 800.0f);
            y2 = fminf(fmaxf(y2, 0.0f), 800.0f);
            bool valid = (x2 - x1 >= 1e-3f) && (y2 - y1 >= 1e-3f);
            box = make_float4(x1, y1, x2, y2);
            lgv = lg;
            unsigned int sk = valid ? dkey_of(lg) : 0xffffffffu;
            key = ((unsigned long long)sk << 27) |
                  ((unsigned long long)(unsigned int)p << 10) | (unsigned long long)j;
        }
        U.srt.s[j] = key;
        U.srt.bx[j] = box;
        U.srt.lg[j] = lgv;
    }
    __syncthreads();

    for (int k = 2; k <= 1024; k <<= 1) {
        for (int j2 = k >> 1; j2 > 0; j2 >>= 1) {
            if (tid < 512) {
                int i = ((tid & ~(j2 - 1)) << 1) | (tid & (j2 - 1));
                int ix = i | j2;
                bool up = ((i & k) == 0);
                unsigned long long A = U.srt.s[i], B = U.srt.s[ix];
                if ((A > B) == up) { U.srt.s[i] = B; U.srt.s[ix] = A; }
            }
            __syncthreads();
        }
    }
    {
        int e = tid;
        unsigned long long key = U.srt.s[e];
        int j = (int)(key & 0x3ffull);
        skey[(size_t)nl * 1024 + e] = key;
        sboxL[(size_t)nl * 1024 + e] = U.srt.bx[j];
        slogL[(size_t)nl * 1024 + e] = U.srt.lg[j];
        bool v = (key >> 27) != 0xFFFFFFFFull;
        bool vn = (e < 1023) ? ((U.srt.s[e + 1] >> 27) != 0xFFFFFFFFull) : false;
        if (e == 0 && !v) ccnt[nl] = 0;
        if (v && (e == 1023 || !vn)) ccnt[nl] = e + 1;
    }
}

__global__ __launch_bounds__(256) void k_mask(const float4* sboxL, const int* ccnt,
                                              unsigned long long* MT) {
#pragma clang fp contract(off)
    int n = blockIdx.z, l = blockIdx.y;
    int ci = blockIdx.x >> 4, cj = blockIdx.x & 15;
    int nl = n * NLV + l;
    int cnt = ccnt[nl];
    int nw = (cnt + 63) / 64;
    if (cj < ci || cj >= nw) return;
    __shared__ float4 bi[64], bj[64];
    int tid = threadIdx.x;
    float off = (float)l * 801.0f;
    if (tid < 64) {
        float4 b = sboxL[nl * 1024 + cj * 64 + tid];
        bj[tid] = make_float4(b.x + off, b.y + off, b.z + off, b.w + off);
    } else if (tid < 128) {
        float4 b = sboxL[nl * 1024 + ci * 64 + (tid - 64)];
        bi[tid - 64] = make_float4(b.x + off, b.y + off, b.z + off, b.w + off);
    }
    __syncthreads();
    int w = tid >> 6, lane = tid & 63;
    float4 B = bj[lane];
    float a2 = (B.z - B.x) * (B.w - B.y);
    unsigned long long* outp = MT + ((size_t)nl * 16 + cj) * 1024 + ci * 64;
    #pragma unroll
    for (int t = 0; t < 16; ++t) {
        int i = w * 16 + t;
        float4 A = bi[i];
        float a1 = (A.z - A.x) * (A.w - A.y);
        float ltx = fmaxf(A.x, B.x), lty = fmaxf(A.y, B.y);
        float rbx = fminf(A.z, B.z), rby = fminf(A.w, B.w);
        float wx = fmaxf(rbx - ltx, 0.f), wy = fmaxf(rby - lty, 0.f);
        float inter = wx * wy;
        float iou = inter / ((a1 + a2) - inter);
        unsigned long long word = __ballot(iou > 0.7f);
        if (lane == 0) outp[i] = word;
    }
}

__global__ __launch_bounds__(1024) void k_scan(const unsigned long long* MT,
                                               const int* ccnt,
                                               unsigned long long* keepL,
                                               float* out) {
    int l = blockIdx.x, n = blockIdx.y;
    int nl = n * NLV + l;
    int tid = threadIdx.x, w = tid >> 6, lane = tid & 63;
    __shared__ unsigned long long pendS[16];
    __shared__ unsigned long long defS[16];
    {
        int seg = POSTN / NLV;
        for (int i = tid; i < seg; i += 1024) {
            int idx = n * POSTN + l * seg + i;
            ((float4*)out)[idx] = make_float4(0.f, 0.f, 0.f, 0.f);
            out[NIMG * POSTN * 4 + idx] = 0.f;
        }
    }
    int cnt = ccnt[nl];
    int nw = (cnt + 63) / 64;

    const unsigned long long* base = MT + ((size_t)nl * 16 + w) * 1024;
    unsigned long long Dmask = 0;
    if (w < nw)
        Dmask = base[(size_t)w * 64 + lane] & ~((2ull << lane) - 1ull);
    unsigned long long rows[15];
    #pragma unroll
    for (int cc = 0; cc < 15; ++cc)
        rows[cc] = (cc < w && w < nw) ? base[(size_t)cc * 64 + lane] : 0ull;

    int nb = max(0, min(64, cnt - w * 64));
    unsigned long long pend_w = (nb == 64) ? ~0ull : ((nb > 0) ? ((1ull << nb) - 1ull) : 0ull);
    unsigned long long K_w = 0;
    if (lane == 0) pendS[w] = pend_w;
    __syncthreads();

    for (int round = 0; round < 1024; ++round) {
        unsigned long long any = 0;
        #pragma unroll
        for (int cc = 0; cc < 16; ++cc) any |= pendS[cc];
        if (!any) break;
        unsigned long long acc = ((pendS[w] >> lane) & 1ull) ? Dmask : 0ull;
        #pragma unroll
        for (int cc = 0; cc < 15; ++cc)
            if (cc < w) acc |= ((pendS[cc] >> lane) & 1ull) ? rows[cc] : 0ull;
        unsigned int vlo = (unsigned int)acc, vhi = (unsigned int)(acc >> 32);
        #pragma unroll
        for (int m = 1; m < 64; m <<= 1) {
            vlo |= (unsigned int)__shfl_xor((int)vlo, m, 64);
            vhi |= (unsigned int)__shfl_xor((int)vhi, m, 64);
        }
        unsigned long long sup = ((unsigned long long)vhi << 32) | (unsigned long long)vlo;
        unsigned long long def_w = pend_w & ~sup;
        K_w |= def_w;
        if (lane == 0) defS[w] = def_w;
        __syncthreads();
        unsigned long long acc2 = ((defS[w] >> lane) & 1ull) ? Dmask : 0ull;
        #pragma unroll
        for (int cc = 0; cc < 15; ++cc)
            if (cc < w) acc2 |= ((defS[cc] >> lane) & 1ull) ? rows[cc] : 0ull;
        unsigned int rlo = (unsigned int)acc2, rhi = (unsigned int)(acc2 >> 32);
        #pragma unroll
        for (int m = 1; m < 64; m <<= 1) {
            rlo |= (unsigned int)__shfl_xor((int)rlo, m, 64);
            rhi |= (unsigned int)__shfl_xor((int)rhi, m, 64);
        }
        unsigned long long rem = ((unsigned long long)rhi << 32) | (unsigned long long)rlo;
        pend_w &= ~def_w & ~rem;
        if (lane == 0) pendS[w] = pend_w;
        __syncthreads();
    }
    if (lane == 0) keepL[nl * 16 + w] = K_w;
}

__global__ __launch_bounds__(1024) void k_rank(const unsigned long long* skey,
                                               const unsigned long long* keepL,
                                               const int* ccnt,
                                               const float4* sboxL, const float* slogL,
                                               float* out) {
    int l = blockIdx.x, n = blockIdx.y;
    int tid = threadIdx.x;
    __shared__ unsigned long long KS[NLV][1024];
    __shared__ unsigned long long kd[NLV][16];
    __shared__ int kpre[NLV][17];
    __shared__ int lcnt[NLV];
    for (int e = tid; e < NLV * 1024; e += 1024)
        ((unsigned long long*)KS)[e] = skey[(size_t)n * NLV * 1024 + e];
    if (tid < NLV * 16) ((unsigned long long*)kd)[tid] = keepL[n * NLV * 16 + tid];
    if (tid < NLV) lcnt[tid] = ccnt[n * NLV + tid];
    __syncthreads();
    if (tid < NLV) {
        int run = 0;
        for (int q = 0; q < 16; ++q) { kpre[tid][q] = run; run += (int)__popcll(kd[tid][q]); }
        kpre[tid][16] = run;
    }
    __syncthreads();
    int i = tid;
    if (i >= lcnt[l]) return;
    int q = i >> 6, b = i & 63;
    if (!((kd[l][q] >> b) & 1ull)) return;
    int rank = kpre[l][q] + (int)__popcll(kd[l][q] & ((1ull << b) - 1ull));
    unsigned int sk = (unsigned int)(KS[l][i] >> 27);
    for (int l2 = 0; l2 < NLV; ++l2) {
        if (l2 == l) continue;
        int c2 = lcnt[l2];
        unsigned long long bound = (l2 < l)
            ? (((unsigned long long)sk + 1ull) << 27)
            : ((unsigned long long)sk << 27);
        int lo = 0, hi = c2;
        while (lo < hi) {
            int mid = (lo + hi) >> 1;
            if (KS[l2][mid] < bound) lo = mid + 1; else hi = mid;
        }
        int mq = lo >> 6, mb = lo & 63;
        rank += kpre[l2][mq] + (mb ? (int)__popcll(kd[l2][mq] & ((1ull << mb) - 1ull)) : 0);
    }
    if (rank < POSTN) {
        ((float4*)out)[n * POSTN + rank] = sboxL[(size_t)(n * NLV + l) * 1024 + i];
        float lg = slogL[(size_t)(n * NLV + l) * 1024 + i];
        out[NIMG * POSTN * 4 + n * POSTN + rank] = 1.0f / (1.0f + expf(-lg));
    }
}

extern "C" void kernel_launch(void* const* d_in, const int* in_sizes, int n_in,
                              void* d_out, int out_size, void* d_ws, size_t ws_size,
                              hipStream_t stream) {
    Ptrs P;
    bool interleaved = (in_sizes[1] == 4 * in_sizes[0]);
    for (int i = 0; i < NLV; ++i) {
        if (interleaved) {
            P.obj[i] = (const float*)d_in[2 * i];
            P.del[i] = (const float*)d_in[2 * i + 1];
        } else {
            P.obj[i] = (const float*)d_in[i];
            P.del[i] = (const float*)d_in[NLV + i];
        }
    }
    P.anch = (const float*)d_in[10];

    char* w = (char*)d_ws;
    size_t off = 0;
    auto alloc = [&](size_t bytes) {
        void* p = w + off;
        off = (off + bytes + 255) & ~(size_t)255;
        return p;
    };
    const size_t NLT = (size_t)NIMG * NLV * 1024;
    unsigned int* hist = (unsigned int*)alloc((size_t)NIMG * NLV * NHB * 2048 * 4);
    int* scnt = (int*)alloc(256);
    int* tcnt = (int*)alloc(256);
    unsigned int* thr = (unsigned int*)alloc((size_t)NIMG * NLV * 2 * 4);
    unsigned long long* tiebuf = (unsigned long long*)alloc((size_t)NIMG * NLV * TCAP * 8);
    int* cgv     = (int*)alloc((size_t)TSEL * 4);
    float* clv   = (float*)alloc((size_t)TSEL * 4);
    unsigned long long* skey = (unsigned long long*)alloc(NLT * 8);
    float4* sboxL = (float4*)alloc(NLT * 16);
    float* slogL  = (float*)alloc(NLT * 4);
    int* ccnt    = (int*)alloc((size_t)NIMG * NLV * 4);
    unsigned long long* keepL = (unsigned long long*)alloc((size_t)NIMG * NLV * 16 * 8);
    unsigned long long* MT = (unsigned long long*)alloc((size_t)NIMG * NLV * 16 * 1024 * 8);
    float* outp = (float*)d_out;
    (void)ws_size; (void)n_in;

    void* args[] = { (void*)&P, (void*)&hist, (void*)&scnt, (void*)&tcnt,
                     (void*)&thr, (void*)&tiebuf, (void*)&cgv, (void*)&clv,
                     (void*)&skey, (void*)&sboxL, (void*)&slogL, (void*)&ccnt,
                     (void*)&keepL, (void*)&MT, (void*)&outp };
    hipError_t e = hipLaunchCooperativeKernel((const void*)k_all, dim3(GRID),
                                              dim3(1024), args, 0, stream);
    if (e != hipSuccess) {
        (void)hipGetLastError();   // clear; fall back to proven 7-kernel path
        k_hist<<<dim3(NHB, NLV, NIMG), 256, 0, stream>>>(P, hist);
        k_thresh<<<NIMG * NLV, 1024, 0, stream>>>(hist, thr, scnt, tcnt);
        k_pick<<<dim3(PBLK, NLV, NIMG), 256, 0, stream>>>(P, thr, scnt, tcnt, cgv, clv, tiebuf);
        k_tbs<<<dim3(NLV, NIMG), 1024, 0, stream>>>(P, thr, tcnt, tiebuf, cgv, clv,
                                                    skey, sboxL, slogL, ccnt);
        k_mask<<<dim3(256, NLV, NIMG), 256, 0, stream>>>(sboxL, ccnt, MT);
        k_scan<<<dim3(NLV, NIMG), 1024, 0, stream>>>(MT, ccnt, keepL, outp);
        k_rank<<<dim3(NLV, NIMG), 1024, 0, stream>>>(skey, keepL, ccnt, sboxL, slogL, outp);
    }
}